// Round 10
// baseline (832.705 us; speedup 1.0000x reference)
//
#include <hip/hip_runtime.h>
#include <cstddef>

// UniPhyBlock on gfx950 — f32 inputs, f32 internal pipeline, F32 OUTPUT. 7 kernels.
// Shapes: B=2,T=16,D=32,H=64,W=64, C2=64, E4=256. NTOK=131072, ND=NTOK*32=4194304.
// Output layout (round 10): PLANAR f32 — stack([x.real, x.imag], axis=0) of
//   [B,T,D,H,W]: out[cidx] = real, out[ND + cidx] = imag,
//   cidx = ((b*16+t)*32+d)*4096 + h*64 + w.
//   (Round-9 established the buffer is f32 x 8388608: 33.5 MB of f32 writes did
//    not fault and read back sane; interleaved order failed -> test planar.
//    This also covers the "expected = real part only, out_size=4194304" world.)
// ws (f32): [0]=zn_re (later x_re), [1]=zn_im (later x_im), [2]=cliff_re,
//           [3]=cliff_im, [4]=freq_re, [5]=freq_im  -> 6*ND*4B = 96 MB.

#define EPS_ 1e-5f
#define PI_  3.14159265358979323846f
#define ND_  4194304ull

// ---------------- K1: input transpose + spatial cnorm ----------------
__global__ __launch_bounds__(256) void k1_cnorm_spatial(
    const float* __restrict__ xr, const float* __restrict__ xi,
    const float* __restrict__ g, const float* __restrict__ b,
    float* __restrict__ znr, float* __restrict__ zni) {
  int tok = blockIdx.x * 256 + threadIdx.x;      // (bt,h,w)
  int bt = tok >> 12;
  int hw = tok & 4095;
  const float* pr = xr + (size_t)bt * 131072 + hw;   // bt*D*HW
  const float* pi = xi + (size_t)bt * 131072 + hw;
  float r[32], q[32];
  float s = 0.f;
#pragma unroll
  for (int d = 0; d < 32; d++) {
    r[d] = pr[(size_t)d * 4096];
    q[d] = pi[(size_t)d * 4096];
    s += r[d] + q[d];
  }
  float mu = s * 0.015625f;
  float v = 0.f;
#pragma unroll
  for (int d = 0; d < 32; d++) {
    float a = r[d] - mu, c = q[d] - mu;
    v += a * a + c * c;
  }
  float rstd = rsqrtf(v * 0.015625f + EPS_);
#pragma unroll
  for (int d = 0; d < 32; d++) {
    r[d] = (r[d] - mu) * rstd * g[d] + b[d];
    q[d] = (q[d] - mu) * rstd * g[32 + d] + b[32 + d];
  }
  float4* outr = (float4*)(znr + (size_t)tok * 32);
  float4* outi = (float4*)(zni + (size_t)tok * 32);
#pragma unroll
  for (int j = 0; j < 8; j++) {
    outr[j] = make_float4(r[4 * j], r[4 * j + 1], r[4 * j + 2], r[4 * j + 3]);
    outi[j] = make_float4(q[4 * j], q[4 * j + 1], q[4 * j + 2], q[4 * j + 3]);
  }
}

// ---------------- K2: 3x3 SAME conv, 64->64 channels (NHWC) ----------------
__global__ __launch_bounds__(256) void k2_conv(
    const float* __restrict__ znr, const float* __restrict__ zni,
    const float* __restrict__ wgt, const float* __restrict__ bias,
    float* __restrict__ clr, float* __restrict__ cli) {
  __shared__ float stile[3 * 64 * 65];  // [row][w][c], pad 65
  int h = blockIdx.x, bt = blockIdx.y;
  for (int i = threadIdx.x; i < 3 * 64 * 64; i += 256) {
    int rr = i >> 12;
    int rem = i & 4095;
    int w = rem >> 6, c = rem & 63;
    int hh = h + rr - 1;
    float v = 0.f;
    if ((unsigned)hh < 64u) {
      int tok = (bt * 64 + hh) * 64 + w;
      v = (c < 32) ? znr[(size_t)tok * 32 + c] : zni[(size_t)tok * 32 + c - 32];
    }
    stile[(rr * 64 + w) * 65 + c] = v;
  }
  __syncthreads();
  int wt = threadIdx.x & 31;   // w slots: wt, wt+32
  int ocg = threadIdx.x >> 5;  // 0..7 -> oc = ocg*8
  int oc = ocg * 8;
  float acc0[8], acc1[8];
#pragma unroll
  for (int k = 0; k < 8; k++) {
    float bz = bias[oc + k];
    acc0[k] = bz;
    acc1[k] = bz;
  }
  for (int kh = 0; kh < 3; kh++) {
#pragma unroll
    for (int kw = 0; kw < 3; kw++) {
      int w0 = wt + kw - 1;
      int w1 = wt + 32 + kw - 1;
      bool v0 = (unsigned)w0 < 64u;
      bool v1 = (unsigned)w1 < 64u;
      const float* s0 = &stile[(kh * 64 + (v0 ? w0 : 0)) * 65];
      const float* s1 = &stile[(kh * 64 + (v1 ? w1 : 0)) * 65];
      const float* wp = wgt + (size_t)((kh * 3 + kw) * 64) * 64 + oc;
      for (int ic = 0; ic < 64; ic++) {
        float a0 = v0 ? s0[ic] : 0.f;
        float a1 = v1 ? s1[ic] : 0.f;
        const float* wrow = wp + (size_t)ic * 64;
        float4 wa = *(const float4*)(wrow);
        float4 wb = *(const float4*)(wrow + 4);
        float wv[8] = {wa.x, wa.y, wa.z, wa.w, wb.x, wb.y, wb.z, wb.w};
#pragma unroll
        for (int k = 0; k < 8; k++) {
          acc0[k] += a0 * wv[k];
          acc1[k] += a1 * wv[k];
        }
      }
    }
  }
  int tok0 = (bt * 64 + h) * 64;
  if (ocg < 4) {
    float* p0 = clr + (size_t)(tok0 + wt) * 32 + oc;
    float* p1 = clr + (size_t)(tok0 + wt + 32) * 32 + oc;
    *(float4*)(p0) = make_float4(acc0[0], acc0[1], acc0[2], acc0[3]);
    *(float4*)(p0 + 4) = make_float4(acc0[4], acc0[5], acc0[6], acc0[7]);
    *(float4*)(p1) = make_float4(acc1[0], acc1[1], acc1[2], acc1[3]);
    *(float4*)(p1 + 4) = make_float4(acc1[4], acc1[5], acc1[6], acc1[7]);
  } else {
    int oc2 = oc - 32;
    float* p0 = cli + (size_t)(tok0 + wt) * 32 + oc2;
    float* p1 = cli + (size_t)(tok0 + wt + 32) * 32 + oc2;
    *(float4*)(p0) = make_float4(acc0[0], acc0[1], acc0[2], acc0[3]);
    *(float4*)(p0 + 4) = make_float4(acc0[4], acc0[5], acc0[6], acc0[7]);
    *(float4*)(p1) = make_float4(acc1[0], acc1[1], acc1[2], acc1[3]);
    *(float4*)(p1 + 4) = make_float4(acc1[4], acc1[5], acc1[6], acc1[7]);
  }
}

// ---------------- K3: forward DFT along W ----------------
__global__ __launch_bounds__(256) void k3_dftw(
    const float* __restrict__ znr, const float* __restrict__ zni,
    float* __restrict__ fqr, float* __restrict__ fqi) {
  __shared__ float sr[2048], si[2048];
  __shared__ float twr[64], twi[64];
  int h = blockIdx.x, bt = blockIdx.y;
  size_t base = (size_t)((bt * 64 + h) * 64) * 32;
  if (threadIdx.x < 64) {
    float ang = -2.f * PI_ * (float)threadIdx.x * (1.f / 64.f);
    twr[threadIdx.x] = cosf(ang);
    twi[threadIdx.x] = sinf(ang);
  }
  for (int i = threadIdx.x; i < 2048; i += 256) {
    sr[i] = znr[base + i];
    si[i] = zni[base + i];
  }
  __syncthreads();
  int k = threadIdx.x & 63;
  int dbase = (threadIdx.x >> 6) * 8;
  float ar[8] = {0, 0, 0, 0, 0, 0, 0, 0}, ai[8] = {0, 0, 0, 0, 0, 0, 0, 0};
  for (int w = 0; w < 64; w++) {
    int idx = (w * k) & 63;
    float tr = twr[idx], ti = twi[idx];
    const float4* pr4 = (const float4*)&sr[w * 32 + dbase];
    const float4* pi4 = (const float4*)&si[w * 32 + dbase];
    float4 a0 = pr4[0], a1 = pr4[1], b0 = pi4[0], b1 = pi4[1];
    float rr[8] = {a0.x, a0.y, a0.z, a0.w, a1.x, a1.y, a1.z, a1.w};
    float ii[8] = {b0.x, b0.y, b0.z, b0.w, b1.x, b1.y, b1.z, b1.w};
#pragma unroll
    for (int j = 0; j < 8; j++) {
      ar[j] += rr[j] * tr - ii[j] * ti;
      ai[j] += rr[j] * ti + ii[j] * tr;
    }
  }
  __syncthreads();
#pragma unroll
  for (int j = 0; j < 8; j++) {
    sr[k * 32 + dbase + j] = ar[j];
    si[k * 32 + dbase + j] = ai[j];
  }
  __syncthreads();
  for (int i = threadIdx.x; i < 2048; i += 256) {
    fqr[base + i] = sr[i];
    fqi[base + i] = si[i];
  }
}

// ---------------- K4: fwd DFT along H, * filt, inv DFT along H (in place) ----------------
__global__ __launch_bounds__(256) void k4_dfth(
    float* __restrict__ fqr, float* __restrict__ fqi,
    const float* __restrict__ flr, const float* __restrict__ fli) {
  __shared__ float sr[2048], si[2048], Fr[2048], Fi[2048];
  __shared__ float twr[64], twi[64];
  int kw = blockIdx.x, bt = blockIdx.y;
  if (threadIdx.x < 64) {
    float ang = -2.f * PI_ * (float)threadIdx.x * (1.f / 64.f);
    twr[threadIdx.x] = cosf(ang);
    twi[threadIdx.x] = sinf(ang);
  }
  for (int i = threadIdx.x; i < 2048; i += 256) {
    int hh = i >> 5, d = i & 31;
    size_t ga = (size_t)((bt * 64 + hh) * 64 + kw) * 32 + d;
    sr[i] = fqr[ga];
    si[i] = fqi[ga];
  }
  __syncthreads();
  int kh = threadIdx.x & 63;
  int dbase = (threadIdx.x >> 6) * 8;
  {
    float ar[8] = {0, 0, 0, 0, 0, 0, 0, 0}, ai[8] = {0, 0, 0, 0, 0, 0, 0, 0};
    for (int hh = 0; hh < 64; hh++) {
      int idx = (hh * kh) & 63;
      float tr = twr[idx], ti = twi[idx];
      const float4* pr4 = (const float4*)&sr[hh * 32 + dbase];
      const float4* pi4 = (const float4*)&si[hh * 32 + dbase];
      float4 a0 = pr4[0], a1 = pr4[1], b0 = pi4[0], b1 = pi4[1];
      float rr[8] = {a0.x, a0.y, a0.z, a0.w, a1.x, a1.y, a1.z, a1.w};
      float ii[8] = {b0.x, b0.y, b0.z, b0.w, b1.x, b1.y, b1.z, b1.w};
#pragma unroll
      for (int j = 0; j < 8; j++) {
        ar[j] += rr[j] * tr - ii[j] * ti;
        ai[j] += rr[j] * ti + ii[j] * tr;
      }
    }
    // multiply by filt[kh][kw][d]
    const float4* fr4 = (const float4*)&flr[(size_t)(kh * 64 + kw) * 32 + dbase];
    const float4* fi4 = (const float4*)&fli[(size_t)(kh * 64 + kw) * 32 + dbase];
    float4 f0 = fr4[0], f1 = fr4[1], g0 = fi4[0], g1 = fi4[1];
    float fre[8] = {f0.x, f0.y, f0.z, f0.w, f1.x, f1.y, f1.z, f1.w};
    float fim[8] = {g0.x, g0.y, g0.z, g0.w, g1.x, g1.y, g1.z, g1.w};
#pragma unroll
    for (int j = 0; j < 8; j++) {
      float pr = ar[j] * fre[j] - ai[j] * fim[j];
      float pi = ar[j] * fim[j] + ai[j] * fre[j];
      Fr[kh * 32 + dbase + j] = pr;
      Fi[kh * 32 + dbase + j] = pi;
    }
  }
  __syncthreads();
  int hh2 = threadIdx.x & 63;
  {
    float ar[8] = {0, 0, 0, 0, 0, 0, 0, 0}, ai[8] = {0, 0, 0, 0, 0, 0, 0, 0};
    for (int k2 = 0; k2 < 64; k2++) {
      int idx = (hh2 * k2) & 63;
      float tr = twr[idx], ti = -twi[idx];  // conj -> inverse
      const float4* pr4 = (const float4*)&Fr[k2 * 32 + dbase];
      const float4* pi4 = (const float4*)&Fi[k2 * 32 + dbase];
      float4 a0 = pr4[0], a1 = pr4[1], b0 = pi4[0], b1 = pi4[1];
      float rr[8] = {a0.x, a0.y, a0.z, a0.w, a1.x, a1.y, a1.z, a1.w};
      float ii[8] = {b0.x, b0.y, b0.z, b0.w, b1.x, b1.y, b1.z, b1.w};
#pragma unroll
      for (int j = 0; j < 8; j++) {
        ar[j] += rr[j] * tr - ii[j] * ti;
        ai[j] += rr[j] * ti + ii[j] * tr;
      }
    }
#pragma unroll
    for (int j = 0; j < 8; j++) {
      sr[hh2 * 32 + dbase + j] = ar[j] * 0.015625f;  // 1/64 (H-inverse)
      si[hh2 * 32 + dbase + j] = ai[j] * 0.015625f;
    }
  }
  __syncthreads();
  for (int i = threadIdx.x; i < 2048; i += 256) {
    int hh = i >> 5, d = i & 31;
    size_t ga = (size_t)((bt * 64 + hh) * 64 + kw) * 32 + d;
    fqr[ga] = sr[i];
    fqi[ga] = si[i];
  }
}

// ---------------- K5: inv DFT along W + gate combine + residual -> x ----------------
__global__ __launch_bounds__(256) void k5_idftw_combine(
    const float* __restrict__ fqr, const float* __restrict__ fqi,
    const float* __restrict__ clr, const float* __restrict__ cli,
    const float* __restrict__ xr_in, const float* __restrict__ xi_in,
    const float* __restrict__ gate,
    float* __restrict__ xr, float* __restrict__ xi) {
  __shared__ float sr[2048], si[2048];
  __shared__ float twr[64], twi[64];
  int h = blockIdx.x, bt = blockIdx.y;
  size_t base = (size_t)((bt * 64 + h) * 64) * 32;
  if (threadIdx.x < 64) {
    float ang = -2.f * PI_ * (float)threadIdx.x * (1.f / 64.f);
    twr[threadIdx.x] = cosf(ang);
    twi[threadIdx.x] = sinf(ang);
  }
  for (int i = threadIdx.x; i < 2048; i += 256) {
    sr[i] = fqr[base + i];
    si[i] = fqi[base + i];
  }
  __syncthreads();
  int w = threadIdx.x & 63;
  int dbase = (threadIdx.x >> 6) * 8;
  float ar[8] = {0, 0, 0, 0, 0, 0, 0, 0}, ai[8] = {0, 0, 0, 0, 0, 0, 0, 0};
  for (int kw = 0; kw < 64; kw++) {
    int idx = (w * kw) & 63;
    float tr = twr[idx], ti = -twi[idx];
    const float4* pr4 = (const float4*)&sr[kw * 32 + dbase];
    const float4* pi4 = (const float4*)&si[kw * 32 + dbase];
    float4 a0 = pr4[0], a1 = pr4[1], b0 = pi4[0], b1 = pi4[1];
    float rr[8] = {a0.x, a0.y, a0.z, a0.w, a1.x, a1.y, a1.z, a1.w};
    float ii[8] = {b0.x, b0.y, b0.z, b0.w, b1.x, b1.y, b1.z, b1.w};
#pragma unroll
    for (int j = 0; j < 8; j++) {
      ar[j] += rr[j] * tr - ii[j] * ti;
      ai[j] += rr[j] * ti + ii[j] * tr;
    }
  }
  float g = gate[0];
  float gi = 1.f - g;
  const float4* c4r = (const float4*)&clr[base + w * 32 + dbase];
  const float4* c4i = (const float4*)&cli[base + w * 32 + dbase];
  float4 cr0 = c4r[0], cr1 = c4r[1], ci0 = c4i[0], ci1 = c4i[1];
  float cre[8] = {cr0.x, cr0.y, cr0.z, cr0.w, cr1.x, cr1.y, cr1.z, cr1.w};
  float cim[8] = {ci0.x, ci0.y, ci0.z, ci0.w, ci1.x, ci1.y, ci1.z, ci1.w};
  float orr[8], oii[8];
#pragma unroll
  for (int j = 0; j < 8; j++) {
    int d = dbase + j;
    size_t ga = (size_t)(bt * 32 + d) * 4096 + h * 64 + w;  // input [B,T,D,H,W]
    orr[j] = g * cre[j] + gi * (ar[j] * 0.015625f) + xr_in[ga];
    oii[j] = g * cim[j] + gi * (ai[j] * 0.015625f) + xi_in[ga];
  }
  __syncthreads();
#pragma unroll
  for (int j = 0; j < 8; j++) {
    sr[w * 32 + dbase + j] = orr[j];
    si[w * 32 + dbase + j] = oii[j];
  }
  __syncthreads();
  for (int i = threadIdx.x; i < 2048; i += 256) {
    xr[base + i] = sr[i];
    xi[base + i] = si[i];
  }
}

// ---------------- K6: temporal cnorm + eigen encode + decay scan + decode ----------------
__global__ __launch_bounds__(256) void k6_temporal(
    float* __restrict__ xr, float* __restrict__ xi,
    const float* __restrict__ lamr, const float* __restrict__ lami,
    const float* __restrict__ Er, const float* __restrict__ Ei,
    const float* __restrict__ Dmr, const float* __restrict__ Dmi,
    const float* __restrict__ lg, const float* __restrict__ lb,
    const float* __restrict__ dtp) {
  __shared__ float sEr[1024], sEi[1024], sDr[1024], sDi[1024];
  __shared__ float htr[128 * 33], hti[128 * 33];  // xt, then h (overwritten per t)
  int n0 = blockIdx.x * 8;
  for (int i = threadIdx.x; i < 1024; i += 256) {
    sEr[i] = Er[i];
    sEi[i] = Ei[i];
    sDr[i] = Dmr[i];
    sDi[i] = Dmi[i];
  }
  if (threadIdx.x < 128) {
    int sI = threadIdx.x >> 4;
    int t = threadIdx.x & 15;
    int n = n0 + sI;
    int bb = n >> 12;
    int hw = n & 4095;
    size_t tokb = ((size_t)(bb * 16 + t)) * 4096 + hw;
    const float4* pr = (const float4*)(xr + tokb * 32);
    const float4* pi = (const float4*)(xi + tokb * 32);
    float rv[32], iv[32];
    float s = 0.f;
#pragma unroll
    for (int j = 0; j < 8; j++) {
      float4 a = pr[j];
      float4 c = pi[j];
      rv[4 * j] = a.x; rv[4 * j + 1] = a.y; rv[4 * j + 2] = a.z; rv[4 * j + 3] = a.w;
      iv[4 * j] = c.x; iv[4 * j + 1] = c.y; iv[4 * j + 2] = c.z; iv[4 * j + 3] = c.w;
      s += a.x + a.y + a.z + a.w + c.x + c.y + c.z + c.w;
    }
    float mu = s * 0.015625f;
    float v = 0.f;
#pragma unroll
    for (int d = 0; d < 32; d++) {
      float a = rv[d] - mu, c = iv[d] - mu;
      v += a * a + c * c;
    }
    float rstd = rsqrtf(v * 0.015625f + EPS_);
    int row = threadIdx.x * 33;
#pragma unroll
    for (int d = 0; d < 32; d++) {
      htr[row + d] = (rv[d] - mu) * rstd * lg[d] + lb[d];
      hti[row + d] = (iv[d] - mu) * rstd * lg[32 + d] + lb[32 + d];
    }
  }
  __syncthreads();
  int sI = threadIdx.x >> 5;
  int e = threadIdx.x & 31;
  float dts = dtp[0];
  float lr = lamr[e], li = lami[e];
  float ex = expf(lr * dts);
  float dcr = ex * cosf(li * dts);
  float dci = ex * sinf(li * dts);
  float nr = dcr - 1.f, ni = dci;
  float invden = 1.f / (lr * lr + li * li);
  float fr = (nr * lr + ni * li) * invden;
  float fi = (ni * lr - nr * li) * invden;
  float hr = 0.f, hi = 0.f;
  for (int t = 0; t < 16; t++) {
    int row = (sI * 16 + t) * 33;
    float xer = 0.f, xei = 0.f;
#pragma unroll
    for (int d = 0; d < 32; d++) {
      float a = htr[row + d], c = hti[row + d];
      float er_ = sEr[d * 32 + e], ei_ = sEi[d * 32 + e];
      xer += a * er_ - c * ei_;
      xei += a * ei_ + c * er_;
    }
    float ur = xer * fr - xei * fi;
    float ui = xer * fi + xei * fr;
    float t1 = dcr * hr - dci * hi + ur;
    hi = dcr * hi + dci * hr + ui;
    hr = t1;
    __syncthreads();
    htr[row + e] = hr;
    hti[row + e] = hi;
    __syncthreads();
  }
  for (int t = 0; t < 16; t++) {
    int row = (sI * 16 + t) * 33;
    float acc = 0.f;
#pragma unroll
    for (int d = 0; d < 32; d++) {
      acc += htr[row + d] * sDr[d * 32 + e] - hti[row + d] * sDi[d * 32 + e];
    }
    int n = n0 + sI;
    int bb = n >> 12;
    int hw = n & 4095;
    size_t tokb = ((size_t)(bb * 16 + t)) * 4096 + hw;
    xr[tokb * 32 + e] += acc;  // drift is real-only
  }
}

// ---------------- K7: para pool MLP + residual + output (F32 PLANAR) ----------------
__global__ __launch_bounds__(256) void k7_pool(
    const float* __restrict__ xr, const float* __restrict__ xi,
    const float* __restrict__ pw1, const float* __restrict__ pb1,
    const float* __restrict__ pw2, const float* __restrict__ pb2,
    float* __restrict__ out, long long out_n) {
  __shared__ float xpT[64 * 65];   // [c][tok]
  __shared__ float hidT[64 * 65];  // [e_local][tok]
  __shared__ float wbuf[64 * 68];  // staged weight chunk, transposed [k][oc/e]
  int tok0 = blockIdx.x * 64;
  for (int i = threadIdx.x; i < 4096; i += 256) {
    int tl = i >> 6, c = i & 63;
    float v = (c < 32) ? xr[(size_t)(tok0 + tl) * 32 + c]
                       : xi[(size_t)(tok0 + tl) * 32 + c - 32];
    xpT[c * 65 + tl] = v;
  }
  int tl = threadIdx.x & 63;
  int q = threadIdx.x >> 6;  // 0..3 -> out channels q*16..+15
  float oacc[16];
#pragma unroll
  for (int k = 0; k < 16; k++) oacc[k] = pb2[q * 16 + k];
  for (int ec = 0; ec < 4; ec++) {
    __syncthreads();
    // stage w1 chunk transposed: wbuf[c][el] = w1[ec*64+el][c]
    for (int i = threadIdx.x; i < 4096; i += 256) {
      int el = i >> 6, c = i & 63;
      wbuf[c * 68 + el] = pw1[(size_t)(ec * 64 + el) * 64 + c];
    }
    __syncthreads();
    float hv[16];
#pragma unroll
    for (int k = 0; k < 16; k++) hv[k] = pb1[ec * 64 + q * 16 + k];
    for (int c = 0; c < 64; c++) {
      float xv = xpT[c * 65 + tl];
      const float4* wr = (const float4*)&wbuf[c * 68 + q * 16];
      float4 w0 = wr[0], w1 = wr[1], w2 = wr[2], w3 = wr[3];
      hv[0] += xv * w0.x;  hv[1] += xv * w0.y;  hv[2] += xv * w0.z;  hv[3] += xv * w0.w;
      hv[4] += xv * w1.x;  hv[5] += xv * w1.y;  hv[6] += xv * w1.z;  hv[7] += xv * w1.w;
      hv[8] += xv * w2.x;  hv[9] += xv * w2.y;  hv[10] += xv * w2.z; hv[11] += xv * w2.w;
      hv[12] += xv * w3.x; hv[13] += xv * w3.y; hv[14] += xv * w3.z; hv[15] += xv * w3.w;
    }
    // gelu (tanh approx, jax default) -> hidT
#pragma unroll
    for (int k = 0; k < 16; k++) {
      float x = hv[k];
      float u = 0.7978845608f * (x + 0.044715f * x * x * x);
      float e2 = __expf(2.f * u);
      float th = 1.f - 2.f / (e2 + 1.f);
      hidT[(q * 16 + k) * 65 + tl] = 0.5f * x * (1.f + th);
    }
    __syncthreads();
    // stage w2 chunk transposed: wbuf[cl][oc] = w2[oc][ec*64+cl]
    for (int i = threadIdx.x; i < 4096; i += 256) {
      int oc = i >> 6, cl = i & 63;
      wbuf[cl * 68 + oc] = pw2[(size_t)oc * 256 + ec * 64 + cl];
    }
    __syncthreads();
    for (int c = 0; c < 64; c++) {
      float hvv = hidT[c * 65 + tl];
      const float4* wr = (const float4*)&wbuf[c * 68 + q * 16];
      float4 w0 = wr[0], w1 = wr[1], w2 = wr[2], w3 = wr[3];
      oacc[0] += hvv * w0.x;  oacc[1] += hvv * w0.y;  oacc[2] += hvv * w0.z;  oacc[3] += hvv * w0.w;
      oacc[4] += hvv * w1.x;  oacc[5] += hvv * w1.y;  oacc[6] += hvv * w1.z;  oacc[7] += hvv * w1.w;
      oacc[8] += hvv * w2.x;  oacc[9] += hvv * w2.y;  oacc[10] += hvv * w2.z; oacc[11] += hvv * w2.w;
      oacc[12] += hvv * w3.x; oacc[13] += hvv * w3.y; oacc[14] += hvv * w3.z; oacc[15] += hvv * w3.w;
    }
  }
  int tok = tok0 + tl;
  int bt = tok >> 12;
  int hw = tok & 4095;
#pragma unroll
  for (int k = 0; k < 16; k++) {
    int oc = q * 16 + k;
    float val = oacc[k] + xpT[oc * 65 + tl];  // + residual
    int d = (oc < 32) ? oc : oc - 32;
    size_t cidx = (size_t)(bt * 32 + d) * 4096 + hw;  // [B,T,D,H,W] index
    // PLANAR f32: real plane [0,ND), imag plane [ND,2ND)
    long long pos = (long long)cidx + ((oc < 32) ? 0ll : (long long)ND_);
    if (pos < out_n) out[pos] = val;
  }
}

// ---------------- launch ----------------
extern "C" void kernel_launch(void* const* d_in, const int* in_sizes, int n_in,
                              void* d_out, int out_size, void* d_ws, size_t ws_size,
                              hipStream_t stream) {
  (void)in_sizes; (void)n_in;
  const float* xr_in = (const float*)d_in[0];
  const float* xi_in = (const float*)d_in[1];
  const float* dt = (const float*)d_in[2];
  const float* ln_s_g = (const float*)d_in[3];
  const float* ln_s_b = (const float*)d_in[4];
  const float* conv_w = (const float*)d_in[5];
  const float* conv_b = (const float*)d_in[6];
  const float* spec_fr = (const float*)d_in[7];
  const float* spec_fi = (const float*)d_in[8];
  const float* lam_r = (const float*)d_in[9];
  const float* lam_i = (const float*)d_in[10];
  const float* E_r = (const float*)d_in[11];
  const float* E_i = (const float*)d_in[12];
  const float* Dm_r = (const float*)d_in[13];
  const float* Dm_i = (const float*)d_in[14];
  const float* ln_t_g = (const float*)d_in[15];
  const float* ln_t_b = (const float*)d_in[16];
  const float* pw1 = (const float*)d_in[17];
  const float* pb1 = (const float*)d_in[18];
  const float* pw2 = (const float*)d_in[19];
  const float* pb2 = (const float*)d_in[20];
  const float* gate = (const float*)d_in[21];

  if (ws_size < 6ull * ND_ * 4ull) return;  // need 96 MB f32 scratch

  float* ws = (float*)d_ws;
  float* znr = ws;                 // -> becomes x_re after K5
  float* zni = ws + ND_;           // -> becomes x_im after K5
  float* clr = ws + 2 * ND_;
  float* cli = ws + 3 * ND_;
  float* fqr = ws + 4 * ND_;
  float* fqi = ws + 5 * ND_;
  float* out = (float*)d_out;

  k1_cnorm_spatial<<<512, 256, 0, stream>>>(xr_in, xi_in, ln_s_g, ln_s_b, znr, zni);
  k2_conv<<<dim3(64, 32), 256, 0, stream>>>(znr, zni, conv_w, conv_b, clr, cli);
  k3_dftw<<<dim3(64, 32), 256, 0, stream>>>(znr, zni, fqr, fqi);
  k4_dfth<<<dim3(64, 32), 256, 0, stream>>>(fqr, fqi, spec_fr, spec_fi);
  k5_idftw_combine<<<dim3(64, 32), 256, 0, stream>>>(fqr, fqi, clr, cli, xr_in, xi_in,
                                                     gate, znr, zni);
  k6_temporal<<<1024, 256, 0, stream>>>(znr, zni, lam_r, lam_i, E_r, E_i, Dm_r, Dm_i,
                                        ln_t_g, ln_t_b, dt);
  k7_pool<<<2048, 256, 0, stream>>>(znr, zni, pw1, pb1, pw2, pb2, out, (long long)out_size);
}

// Round 11
// 718.793 us; speedup vs baseline: 1.1585x; 1.1585x over previous
//
#include <hip/hip_runtime.h>
#include <cstddef>

// UniPhyBlock on gfx950 — f32 inputs, f32 internal pipeline, F32 PLANAR OUTPUT.
// Round 11: k2_conv rewritten as bf16-MFMA implicit GEMM (was 325us issue-bound
// f32 FMA with per-thread global weight loads; MfmaUtil=0, VALUBusy=37%).
// Everything else unchanged from the passing round-10 kernel (absmax 0.0625).
// Output: PLANAR f32 — out[cidx]=real, out[ND+cidx]=imag, cidx over [B,T,D,H,W].
// ws (f32): [0]=zn_re (later x_re), [1]=zn_im (later x_im), [2]=cliff_re,
//           [3]=cliff_im, [4]=freq_re, [5]=freq_im  -> 6*ND*4B = 96 MB.

#define EPS_ 1e-5f
#define PI_  3.14159265358979323846f
#define ND_  4194304ull

typedef __attribute__((ext_vector_type(8))) short bf16x8;   // 8 bf16 (4 VGPRs)
typedef __attribute__((ext_vector_type(4))) float f32x4;    // MFMA C/D

__device__ __forceinline__ short f2bf(float f) {
  unsigned u = __float_as_uint(f);
  unsigned r = (u + 0x7fffu + ((u >> 16) & 1u)) >> 16;  // RNE
  return (short)r;
}

// ---------------- K1: input transpose + spatial cnorm ----------------
__global__ __launch_bounds__(256) void k1_cnorm_spatial(
    const float* __restrict__ xr, const float* __restrict__ xi,
    const float* __restrict__ g, const float* __restrict__ b,
    float* __restrict__ znr, float* __restrict__ zni) {
  int tok = blockIdx.x * 256 + threadIdx.x;      // (bt,h,w)
  int bt = tok >> 12;
  int hw = tok & 4095;
  const float* pr = xr + (size_t)bt * 131072 + hw;   // bt*D*HW
  const float* pi = xi + (size_t)bt * 131072 + hw;
  float r[32], q[32];
  float s = 0.f;
#pragma unroll
  for (int d = 0; d < 32; d++) {
    r[d] = pr[(size_t)d * 4096];
    q[d] = pi[(size_t)d * 4096];
    s += r[d] + q[d];
  }
  float mu = s * 0.015625f;
  float v = 0.f;
#pragma unroll
  for (int d = 0; d < 32; d++) {
    float a = r[d] - mu, c = q[d] - mu;
    v += a * a + c * c;
  }
  float rstd = rsqrtf(v * 0.015625f + EPS_);
#pragma unroll
  for (int d = 0; d < 32; d++) {
    r[d] = (r[d] - mu) * rstd * g[d] + b[d];
    q[d] = (q[d] - mu) * rstd * g[32 + d] + b[32 + d];
  }
  float4* outr = (float4*)(znr + (size_t)tok * 32);
  float4* outi = (float4*)(zni + (size_t)tok * 32);
#pragma unroll
  for (int j = 0; j < 8; j++) {
    outr[j] = make_float4(r[4 * j], r[4 * j + 1], r[4 * j + 2], r[4 * j + 3]);
    outi[j] = make_float4(q[4 * j], q[4 * j + 1], q[4 * j + 2], q[4 * j + 3]);
  }
}

// ---------------- K2: 3x3 SAME conv via bf16 MFMA implicit GEMM ----------------
// Block = one (bt,h) output row: M=64 tokens(w) x N=64 oc, K=9*64.
// sA: bf16 activations [3 rows][66 wpos][64 ic], row-stride 88 shorts (16B align,
//     2-way LDS bank aliasing = free). sB: one (kh,kw) weight chunk transposed
//     [oc][ic] bf16, same stride. 4 waves x 4 n-tiles x (9x2) K-steps of
//     v_mfma_f32_16x16x32_bf16; bias preloaded in C; f32 epilogue stores.
__global__ __launch_bounds__(256) void k2_conv(
    const float* __restrict__ znr, const float* __restrict__ zni,
    const float* __restrict__ wgt, const float* __restrict__ bias,
    float* __restrict__ clr, float* __restrict__ cli) {
  __shared__ __align__(16) short sA[3 * 66 * 88];  // 34.8 KB
  __shared__ __align__(16) short sB[64 * 88];      // 11.3 KB
  int h = blockIdx.x, bt = blockIdx.y;
  // stage activations (3 rows, w in [-1,64], 64 ch) as bf16
  for (int i = threadIdx.x; i < 3 * 66 * 64; i += 256) {
    int c = i & 63;
    int wp = (i >> 6) % 66;
    int rr = i / (66 * 64);
    int hh = h + rr - 1;
    int w = wp - 1;
    float v = 0.f;
    if ((unsigned)hh < 64u && (unsigned)w < 64u) {
      int tok = (bt * 64 + hh) * 64 + w;
      v = (c < 32) ? znr[(size_t)tok * 32 + c] : zni[(size_t)tok * 32 + c - 32];
    }
    sA[(rr * 66 + wp) * 88 + c] = f2bf(v);
  }
  int lane = threadIdx.x & 63;
  int wv = threadIdx.x >> 6;
  int m0 = wv * 16;          // this wave's 16-token strip
  int lr = lane & 15;        // A-row / B-col / D-col
  int quad = lane >> 4;      // k-chunk selector; D-row group
  f32x4 acc[4];
#pragma unroll
  for (int nt = 0; nt < 4; nt++) {
    float bz = bias[nt * 16 + lr];
    acc[nt][0] = bz; acc[nt][1] = bz; acc[nt][2] = bz; acc[nt][3] = bz;
  }
  for (int kk = 0; kk < 9; kk++) {
    int kh = kk / 3, kw = kk - kh * 3;
    __syncthreads();
    // stage weight chunk transposed: sB[oc][ic] = wgt[kk][ic][oc]
    for (int i = threadIdx.x; i < 4096; i += 256) {
      int oc = i & 63;
      int ic = i >> 6;
      sB[oc * 88 + ic] = f2bf(wgt[((size_t)kk * 64 + ic) * 64 + oc]);
    }
    __syncthreads();
    // A row for this lane: w_in = (m0+lr) + kw - 1  -> wpos = m0+lr+kw
    const short* arow = &sA[((size_t)kh * 66 + (m0 + lr + kw)) * 88 + quad * 8];
#pragma unroll
    for (int ks = 0; ks < 2; ks++) {
      bf16x8 afrag = *(const bf16x8*)(arow + ks * 32);
#pragma unroll
      for (int nt = 0; nt < 4; nt++) {
        bf16x8 bfrag = *(const bf16x8*)&sB[(size_t)(nt * 16 + lr) * 88 + ks * 32 + quad * 8];
        acc[nt] = __builtin_amdgcn_mfma_f32_16x16x32_bf16(afrag, bfrag, acc[nt], 0, 0, 0);
      }
    }
  }
  // epilogue: D[row=quad*4+reg][col=lr] per n-tile -> clr/cli (f32)
  int tokbase = (bt * 64 + h) * 64 + m0;
#pragma unroll
  for (int nt = 0; nt < 4; nt++) {
    int oc = nt * 16 + lr;
    float* dst = (oc < 32) ? (clr + oc) : (cli + (oc - 32));
#pragma unroll
    for (int reg = 0; reg < 4; reg++) {
      int m = quad * 4 + reg;
      dst[(size_t)(tokbase + m) * 32] = acc[nt][reg];
    }
  }
}

// ---------------- K3: forward DFT along W ----------------
__global__ __launch_bounds__(256) void k3_dftw(
    const float* __restrict__ znr, const float* __restrict__ zni,
    float* __restrict__ fqr, float* __restrict__ fqi) {
  __shared__ float sr[2048], si[2048];
  __shared__ float twr[64], twi[64];
  int h = blockIdx.x, bt = blockIdx.y;
  size_t base = (size_t)((bt * 64 + h) * 64) * 32;
  if (threadIdx.x < 64) {
    float ang = -2.f * PI_ * (float)threadIdx.x * (1.f / 64.f);
    twr[threadIdx.x] = cosf(ang);
    twi[threadIdx.x] = sinf(ang);
  }
  for (int i = threadIdx.x; i < 2048; i += 256) {
    sr[i] = znr[base + i];
    si[i] = zni[base + i];
  }
  __syncthreads();
  int k = threadIdx.x & 63;
  int dbase = (threadIdx.x >> 6) * 8;
  float ar[8] = {0, 0, 0, 0, 0, 0, 0, 0}, ai[8] = {0, 0, 0, 0, 0, 0, 0, 0};
  for (int w = 0; w < 64; w++) {
    int idx = (w * k) & 63;
    float tr = twr[idx], ti = twi[idx];
    const float4* pr4 = (const float4*)&sr[w * 32 + dbase];
    const float4* pi4 = (const float4*)&si[w * 32 + dbase];
    float4 a0 = pr4[0], a1 = pr4[1], b0 = pi4[0], b1 = pi4[1];
    float rr[8] = {a0.x, a0.y, a0.z, a0.w, a1.x, a1.y, a1.z, a1.w};
    float ii[8] = {b0.x, b0.y, b0.z, b0.w, b1.x, b1.y, b1.z, b1.w};
#pragma unroll
    for (int j = 0; j < 8; j++) {
      ar[j] += rr[j] * tr - ii[j] * ti;
      ai[j] += rr[j] * ti + ii[j] * tr;
    }
  }
  __syncthreads();
#pragma unroll
  for (int j = 0; j < 8; j++) {
    sr[k * 32 + dbase + j] = ar[j];
    si[k * 32 + dbase + j] = ai[j];
  }
  __syncthreads();
  for (int i = threadIdx.x; i < 2048; i += 256) {
    fqr[base + i] = sr[i];
    fqi[base + i] = si[i];
  }
}

// ---------------- K4: fwd DFT along H, * filt, inv DFT along H (in place) ----------------
__global__ __launch_bounds__(256) void k4_dfth(
    float* __restrict__ fqr, float* __restrict__ fqi,
    const float* __restrict__ flr, const float* __restrict__ fli) {
  __shared__ float sr[2048], si[2048], Fr[2048], Fi[2048];
  __shared__ float twr[64], twi[64];
  int kw = blockIdx.x, bt = blockIdx.y;
  if (threadIdx.x < 64) {
    float ang = -2.f * PI_ * (float)threadIdx.x * (1.f / 64.f);
    twr[threadIdx.x] = cosf(ang);
    twi[threadIdx.x] = sinf(ang);
  }
  for (int i = threadIdx.x; i < 2048; i += 256) {
    int hh = i >> 5, d = i & 31;
    size_t ga = (size_t)((bt * 64 + hh) * 64 + kw) * 32 + d;
    sr[i] = fqr[ga];
    si[i] = fqi[ga];
  }
  __syncthreads();
  int kh = threadIdx.x & 63;
  int dbase = (threadIdx.x >> 6) * 8;
  {
    float ar[8] = {0, 0, 0, 0, 0, 0, 0, 0}, ai[8] = {0, 0, 0, 0, 0, 0, 0, 0};
    for (int hh = 0; hh < 64; hh++) {
      int idx = (hh * kh) & 63;
      float tr = twr[idx], ti = twi[idx];
      const float4* pr4 = (const float4*)&sr[hh * 32 + dbase];
      const float4* pi4 = (const float4*)&si[hh * 32 + dbase];
      float4 a0 = pr4[0], a1 = pr4[1], b0 = pi4[0], b1 = pi4[1];
      float rr[8] = {a0.x, a0.y, a0.z, a0.w, a1.x, a1.y, a1.z, a1.w};
      float ii[8] = {b0.x, b0.y, b0.z, b0.w, b1.x, b1.y, b1.z, b1.w};
#pragma unroll
      for (int j = 0; j < 8; j++) {
        ar[j] += rr[j] * tr - ii[j] * ti;
        ai[j] += rr[j] * ti + ii[j] * tr;
      }
    }
    // multiply by filt[kh][kw][d]
    const float4* fr4 = (const float4*)&flr[(size_t)(kh * 64 + kw) * 32 + dbase];
    const float4* fi4 = (const float4*)&fli[(size_t)(kh * 64 + kw) * 32 + dbase];
    float4 f0 = fr4[0], f1 = fr4[1], g0 = fi4[0], g1 = fi4[1];
    float fre[8] = {f0.x, f0.y, f0.z, f0.w, f1.x, f1.y, f1.z, f1.w};
    float fim[8] = {g0.x, g0.y, g0.z, g0.w, g1.x, g1.y, g1.z, g1.w};
#pragma unroll
    for (int j = 0; j < 8; j++) {
      float pr = ar[j] * fre[j] - ai[j] * fim[j];
      float pi = ar[j] * fim[j] + ai[j] * fre[j];
      Fr[kh * 32 + dbase + j] = pr;
      Fi[kh * 32 + dbase + j] = pi;
    }
  }
  __syncthreads();
  int hh2 = threadIdx.x & 63;
  {
    float ar[8] = {0, 0, 0, 0, 0, 0, 0, 0}, ai[8] = {0, 0, 0, 0, 0, 0, 0, 0};
    for (int k2 = 0; k2 < 64; k2++) {
      int idx = (hh2 * k2) & 63;
      float tr = twr[idx], ti = -twi[idx];  // conj -> inverse
      const float4* pr4 = (const float4*)&Fr[k2 * 32 + dbase];
      const float4* pi4 = (const float4*)&Fi[k2 * 32 + dbase];
      float4 a0 = pr4[0], a1 = pr4[1], b0 = pi4[0], b1 = pi4[1];
      float rr[8] = {a0.x, a0.y, a0.z, a0.w, a1.x, a1.y, a1.z, a1.w};
      float ii[8] = {b0.x, b0.y, b0.z, b0.w, b1.x, b1.y, b1.z, b1.w};
#pragma unroll
      for (int j = 0; j < 8; j++) {
        ar[j] += rr[j] * tr - ii[j] * ti;
        ai[j] += rr[j] * ti + ii[j] * tr;
      }
    }
#pragma unroll
    for (int j = 0; j < 8; j++) {
      sr[hh2 * 32 + dbase + j] = ar[j] * 0.015625f;  // 1/64 (H-inverse)
      si[hh2 * 32 + dbase + j] = ai[j] * 0.015625f;
    }
  }
  __syncthreads();
  for (int i = threadIdx.x; i < 2048; i += 256) {
    int hh = i >> 5, d = i & 31;
    size_t ga = (size_t)((bt * 64 + hh) * 64 + kw) * 32 + d;
    fqr[ga] = sr[i];
    fqi[ga] = si[i];
  }
}

// ---------------- K5: inv DFT along W + gate combine + residual -> x ----------------
__global__ __launch_bounds__(256) void k5_idftw_combine(
    const float* __restrict__ fqr, const float* __restrict__ fqi,
    const float* __restrict__ clr, const float* __restrict__ cli,
    const float* __restrict__ xr_in, const float* __restrict__ xi_in,
    const float* __restrict__ gate,
    float* __restrict__ xr, float* __restrict__ xi) {
  __shared__ float sr[2048], si[2048];
  __shared__ float twr[64], twi[64];
  int h = blockIdx.x, bt = blockIdx.y;
  size_t base = (size_t)((bt * 64 + h) * 64) * 32;
  if (threadIdx.x < 64) {
    float ang = -2.f * PI_ * (float)threadIdx.x * (1.f / 64.f);
    twr[threadIdx.x] = cosf(ang);
    twi[threadIdx.x] = sinf(ang);
  }
  for (int i = threadIdx.x; i < 2048; i += 256) {
    sr[i] = fqr[base + i];
    si[i] = fqi[base + i];
  }
  __syncthreads();
  int w = threadIdx.x & 63;
  int dbase = (threadIdx.x >> 6) * 8;
  float ar[8] = {0, 0, 0, 0, 0, 0, 0, 0}, ai[8] = {0, 0, 0, 0, 0, 0, 0, 0};
  for (int kw = 0; kw < 64; kw++) {
    int idx = (w * kw) & 63;
    float tr = twr[idx], ti = -twi[idx];
    const float4* pr4 = (const float4*)&sr[kw * 32 + dbase];
    const float4* pi4 = (const float4*)&si[kw * 32 + dbase];
    float4 a0 = pr4[0], a1 = pr4[1], b0 = pi4[0], b1 = pi4[1];
    float rr[8] = {a0.x, a0.y, a0.z, a0.w, a1.x, a1.y, a1.z, a1.w};
    float ii[8] = {b0.x, b0.y, b0.z, b0.w, b1.x, b1.y, b1.z, b1.w};
#pragma unroll
    for (int j = 0; j < 8; j++) {
      ar[j] += rr[j] * tr - ii[j] * ti;
      ai[j] += rr[j] * ti + ii[j] * tr;
    }
  }
  float g = gate[0];
  float gi = 1.f - g;
  const float4* c4r = (const float4*)&clr[base + w * 32 + dbase];
  const float4* c4i = (const float4*)&cli[base + w * 32 + dbase];
  float4 cr0 = c4r[0], cr1 = c4r[1], ci0 = c4i[0], ci1 = c4i[1];
  float cre[8] = {cr0.x, cr0.y, cr0.z, cr0.w, cr1.x, cr1.y, cr1.z, cr1.w};
  float cim[8] = {ci0.x, ci0.y, ci0.z, ci0.w, ci1.x, ci1.y, ci1.z, ci1.w};
  float orr[8], oii[8];
#pragma unroll
  for (int j = 0; j < 8; j++) {
    int d = dbase + j;
    size_t ga = (size_t)(bt * 32 + d) * 4096 + h * 64 + w;  // input [B,T,D,H,W]
    orr[j] = g * cre[j] + gi * (ar[j] * 0.015625f) + xr_in[ga];
    oii[j] = g * cim[j] + gi * (ai[j] * 0.015625f) + xi_in[ga];
  }
  __syncthreads();
#pragma unroll
  for (int j = 0; j < 8; j++) {
    sr[w * 32 + dbase + j] = orr[j];
    si[w * 32 + dbase + j] = oii[j];
  }
  __syncthreads();
  for (int i = threadIdx.x; i < 2048; i += 256) {
    xr[base + i] = sr[i];
    xi[base + i] = si[i];
  }
}

// ---------------- K6: temporal cnorm + eigen encode + decay scan + decode ----------------
__global__ __launch_bounds__(256) void k6_temporal(
    float* __restrict__ xr, float* __restrict__ xi,
    const float* __restrict__ lamr, const float* __restrict__ lami,
    const float* __restrict__ Er, const float* __restrict__ Ei,
    const float* __restrict__ Dmr, const float* __restrict__ Dmi,
    const float* __restrict__ lg, const float* __restrict__ lb,
    const float* __restrict__ dtp) {
  __shared__ float sEr[1024], sEi[1024], sDr[1024], sDi[1024];
  __shared__ float htr[128 * 33], hti[128 * 33];  // xt, then h (overwritten per t)
  int n0 = blockIdx.x * 8;
  for (int i = threadIdx.x; i < 1024; i += 256) {
    sEr[i] = Er[i];
    sEi[i] = Ei[i];
    sDr[i] = Dmr[i];
    sDi[i] = Dmi[i];
  }
  if (threadIdx.x < 128) {
    int sI = threadIdx.x >> 4;
    int t = threadIdx.x & 15;
    int n = n0 + sI;
    int bb = n >> 12;
    int hw = n & 4095;
    size_t tokb = ((size_t)(bb * 16 + t)) * 4096 + hw;
    const float4* pr = (const float4*)(xr + tokb * 32);
    const float4* pi = (const float4*)(xi + tokb * 32);
    float rv[32], iv[32];
    float s = 0.f;
#pragma unroll
    for (int j = 0; j < 8; j++) {
      float4 a = pr[j];
      float4 c = pi[j];
      rv[4 * j] = a.x; rv[4 * j + 1] = a.y; rv[4 * j + 2] = a.z; rv[4 * j + 3] = a.w;
      iv[4 * j] = c.x; iv[4 * j + 1] = c.y; iv[4 * j + 2] = c.z; iv[4 * j + 3] = c.w;
      s += a.x + a.y + a.z + a.w + c.x + c.y + c.z + c.w;
    }
    float mu = s * 0.015625f;
    float v = 0.f;
#pragma unroll
    for (int d = 0; d < 32; d++) {
      float a = rv[d] - mu, c = iv[d] - mu;
      v += a * a + c * c;
    }
    float rstd = rsqrtf(v * 0.015625f + EPS_);
    int row = threadIdx.x * 33;
#pragma unroll
    for (int d = 0; d < 32; d++) {
      htr[row + d] = (rv[d] - mu) * rstd * lg[d] + lb[d];
      hti[row + d] = (iv[d] - mu) * rstd * lg[32 + d] + lb[32 + d];
    }
  }
  __syncthreads();
  int sI = threadIdx.x >> 5;
  int e = threadIdx.x & 31;
  float dts = dtp[0];
  float lr = lamr[e], li = lami[e];
  float ex = expf(lr * dts);
  float dcr = ex * cosf(li * dts);
  float dci = ex * sinf(li * dts);
  float nr = dcr - 1.f, ni = dci;
  float invden = 1.f / (lr * lr + li * li);
  float fr = (nr * lr + ni * li) * invden;
  float fi = (ni * lr - nr * li) * invden;
  float hr = 0.f, hi = 0.f;
  for (int t = 0; t < 16; t++) {
    int row = (sI * 16 + t) * 33;
    float xer = 0.f, xei = 0.f;
#pragma unroll
    for (int d = 0; d < 32; d++) {
      float a = htr[row + d], c = hti[row + d];
      float er_ = sEr[d * 32 + e], ei_ = sEi[d * 32 + e];
      xer += a * er_ - c * ei_;
      xei += a * ei_ + c * er_;
    }
    float ur = xer * fr - xei * fi;
    float ui = xer * fi + xei * fr;
    float t1 = dcr * hr - dci * hi + ur;
    hi = dcr * hi + dci * hr + ui;
    hr = t1;
    __syncthreads();
    htr[row + e] = hr;
    hti[row + e] = hi;
    __syncthreads();
  }
  for (int t = 0; t < 16; t++) {
    int row = (sI * 16 + t) * 33;
    float acc = 0.f;
#pragma unroll
    for (int d = 0; d < 32; d++) {
      acc += htr[row + d] * sDr[d * 32 + e] - hti[row + d] * sDi[d * 32 + e];
    }
    int n = n0 + sI;
    int bb = n >> 12;
    int hw = n & 4095;
    size_t tokb = ((size_t)(bb * 16 + t)) * 4096 + hw;
    xr[tokb * 32 + e] += acc;  // drift is real-only
  }
}

// ---------------- K7: para pool MLP + residual + output (F32 PLANAR) ----------------
__global__ __launch_bounds__(256) void k7_pool(
    const float* __restrict__ xr, const float* __restrict__ xi,
    const float* __restrict__ pw1, const float* __restrict__ pb1,
    const float* __restrict__ pw2, const float* __restrict__ pb2,
    float* __restrict__ out, long long out_n) {
  __shared__ float xpT[64 * 65];   // [c][tok]
  __shared__ float hidT[64 * 65];  // [e_local][tok]
  __shared__ float wbuf[64 * 68];  // staged weight chunk, transposed [k][oc/e]
  int tok0 = blockIdx.x * 64;
  for (int i = threadIdx.x; i < 4096; i += 256) {
    int tl = i >> 6, c = i & 63;
    float v = (c < 32) ? xr[(size_t)(tok0 + tl) * 32 + c]
                       : xi[(size_t)(tok0 + tl) * 32 + c - 32];
    xpT[c * 65 + tl] = v;
  }
  int tl = threadIdx.x & 63;
  int q = threadIdx.x >> 6;  // 0..3 -> out channels q*16..+15
  float oacc[16];
#pragma unroll
  for (int k = 0; k < 16; k++) oacc[k] = pb2[q * 16 + k];
  for (int ec = 0; ec < 4; ec++) {
    __syncthreads();
    // stage w1 chunk transposed: wbuf[c][el] = w1[ec*64+el][c]
    for (int i = threadIdx.x; i < 4096; i += 256) {
      int el = i >> 6, c = i & 63;
      wbuf[c * 68 + el] = pw1[(size_t)(ec * 64 + el) * 64 + c];
    }
    __syncthreads();
    float hv[16];
#pragma unroll
    for (int k = 0; k < 16; k++) hv[k] = pb1[ec * 64 + q * 16 + k];
    for (int c = 0; c < 64; c++) {
      float xv = xpT[c * 65 + tl];
      const float4* wr = (const float4*)&wbuf[c * 68 + q * 16];
      float4 w0 = wr[0], w1 = wr[1], w2 = wr[2], w3 = wr[3];
      hv[0] += xv * w0.x;  hv[1] += xv * w0.y;  hv[2] += xv * w0.z;  hv[3] += xv * w0.w;
      hv[4] += xv * w1.x;  hv[5] += xv * w1.y;  hv[6] += xv * w1.z;  hv[7] += xv * w1.w;
      hv[8] += xv * w2.x;  hv[9] += xv * w2.y;  hv[10] += xv * w2.z; hv[11] += xv * w2.w;
      hv[12] += xv * w3.x; hv[13] += xv * w3.y; hv[14] += xv * w3.z; hv[15] += xv * w3.w;
    }
    // gelu (tanh approx, jax default) -> hidT
#pragma unroll
    for (int k = 0; k < 16; k++) {
      float x = hv[k];
      float u = 0.7978845608f * (x + 0.044715f * x * x * x);
      float e2 = __expf(2.f * u);
      float th = 1.f - 2.f / (e2 + 1.f);
      hidT[(q * 16 + k) * 65 + tl] = 0.5f * x * (1.f + th);
    }
    __syncthreads();
    // stage w2 chunk transposed: wbuf[cl][oc] = w2[oc][ec*64+cl]
    for (int i = threadIdx.x; i < 4096; i += 256) {
      int oc = i >> 6, cl = i & 63;
      wbuf[cl * 68 + oc] = pw2[(size_t)oc * 256 + ec * 64 + cl];
    }
    __syncthreads();
    for (int c = 0; c < 64; c++) {
      float hvv = hidT[c * 65 + tl];
      const float4* wr = (const float4*)&wbuf[c * 68 + q * 16];
      float4 w0 = wr[0], w1 = wr[1], w2 = wr[2], w3 = wr[3];
      oacc[0] += hvv * w0.x;  oacc[1] += hvv * w0.y;  oacc[2] += hvv * w0.z;  oacc[3] += hvv * w0.w;
      oacc[4] += hvv * w1.x;  oacc[5] += hvv * w1.y;  oacc[6] += hvv * w1.z;  oacc[7] += hvv * w1.w;
      oacc[8] += hvv * w2.x;  oacc[9] += hvv * w2.y;  oacc[10] += hvv * w2.z; oacc[11] += hvv * w2.w;
      oacc[12] += hvv * w3.x; oacc[13] += hvv * w3.y; oacc[14] += hvv * w3.z; oacc[15] += hvv * w3.w;
    }
  }
  int tok = tok0 + tl;
  int bt = tok >> 12;
  int hw = tok & 4095;
#pragma unroll
  for (int k = 0; k < 16; k++) {
    int oc = q * 16 + k;
    float val = oacc[k] + xpT[oc * 65 + tl];  // + residual
    int d = (oc < 32) ? oc : oc - 32;
    size_t cidx = (size_t)(bt * 32 + d) * 4096 + hw;  // [B,T,D,H,W] index
    // PLANAR f32: real plane [0,ND), imag plane [ND,2ND)
    long long pos = (long long)cidx + ((oc < 32) ? 0ll : (long long)ND_);
    if (pos < out_n) out[pos] = val;
  }
}

// ---------------- launch ----------------
extern "C" void kernel_launch(void* const* d_in, const int* in_sizes, int n_in,
                              void* d_out, int out_size, void* d_ws, size_t ws_size,
                              hipStream_t stream) {
  (void)in_sizes; (void)n_in;
  const float* xr_in = (const float*)d_in[0];
  const float* xi_in = (const float*)d_in[1];
  const float* dt = (const float*)d_in[2];
  const float* ln_s_g = (const float*)d_in[3];
  const float* ln_s_b = (const float*)d_in[4];
  const float* conv_w = (const float*)d_in[5];
  const float* conv_b = (const float*)d_in[6];
  const float* spec_fr = (const float*)d_in[7];
  const float* spec_fi = (const float*)d_in[8];
  const float* lam_r = (const float*)d_in[9];
  const float* lam_i = (const float*)d_in[10];
  const float* E_r = (const float*)d_in[11];
  const float* E_i = (const float*)d_in[12];
  const float* Dm_r = (const float*)d_in[13];
  const float* Dm_i = (const float*)d_in[14];
  const float* ln_t_g = (const float*)d_in[15];
  const float* ln_t_b = (const float*)d_in[16];
  const float* pw1 = (const float*)d_in[17];
  const float* pb1 = (const float*)d_in[18];
  const float* pw2 = (const float*)d_in[19];
  const float* pb2 = (const float*)d_in[20];
  const float* gate = (const float*)d_in[21];

  if (ws_size < 6ull * ND_ * 4ull) return;  // need 96 MB f32 scratch

  float* ws = (float*)d_ws;
  float* znr = ws;                 // -> becomes x_re after K5
  float* zni = ws + ND_;           // -> becomes x_im after K5
  float* clr = ws + 2 * ND_;
  float* cli = ws + 3 * ND_;
  float* fqr = ws + 4 * ND_;
  float* fqi = ws + 5 * ND_;
  float* out = (float*)d_out;

  k1_cnorm_spatial<<<512, 256, 0, stream>>>(xr_in, xi_in, ln_s_g, ln_s_b, znr, zni);
  k2_conv<<<dim3(64, 32), 256, 0, stream>>>(znr, zni, conv_w, conv_b, clr, cli);
  k3_dftw<<<dim3(64, 32), 256, 0, stream>>>(znr, zni, fqr, fqi);
  k4_dfth<<<dim3(64, 32), 256, 0, stream>>>(fqr, fqi, spec_fr, spec_fi);
  k5_idftw_combine<<<dim3(64, 32), 256, 0, stream>>>(fqr, fqi, clr, cli, xr_in, xi_in,
                                                     gate, znr, zni);
  k6_temporal<<<1024, 256, 0, stream>>>(znr, zni, lam_r, lam_i, E_r, E_i, Dm_r, Dm_i,
                                        ln_t_g, ln_t_b, dt);
  k7_pool<<<2048, 256, 0, stream>>>(znr, zni, pw1, pb1, pw2, pb2, out, (long long)out_size);
}